// Round 1
// baseline (869.569 us; speedup 1.0000x reference)
//
#include <hip/hip_runtime.h>
#include <stdint.h>

typedef float f32x4 __attribute__((ext_vector_type(4)));
typedef short s16x8 __attribute__((ext_vector_type(8)));

// fp32 -> bf16 RTNE, packed pair into one u32
__device__ __forceinline__ unsigned int fpack2(float a, float b){
  unsigned int ua = __float_as_uint(a); ua += 0x7FFFu + ((ua >> 16) & 1u);
  unsigned int ub = __float_as_uint(b); ub += 0x7FFFu + ((ub >> 16) & 1u);
  return (ua >> 16) | (ub & 0xFFFF0000u);
}
__device__ __forceinline__ unsigned short f2bf(float f){
  unsigned int u = __float_as_uint(f);
  u += 0x7FFFu + ((u >> 16) & 1u);
  return (unsigned short)(u >> 16);
}

// Pack W fp32 [512][512] row-major -> bf16 in MFMA B-fragment order:
// wp[((kt*32 + ntg)*64 + q*16 + c)*8 + j] = W[kt*32 + q*8 + j][ntg*16 + c]
__global__ __launch_bounds__(256) void k_pack_w(const float* __restrict__ W,
                                                unsigned short* __restrict__ wp){
  int idx = blockIdx.x * 256 + threadIdx.x;   // 0..262143
  int k = idx >> 9, n = idx & 511;
  int kt = k >> 5, kr = k & 31;
  int q  = kr >> 3, j = kr & 7;
  int ntg = n >> 4, c = n & 15;
  wp[((kt*32 + ntg)*64 + q*16 + c)*8 + j] = f2bf(W[idx]);
}

// Fused GAT: 4 graphs (48 rows) per 256-thread workgroup.
__global__ __launch_bounds__(256, 2) void k_gat(
    const float* __restrict__ x, const float* __restrict__ adjm,
    const unsigned short* __restrict__ wp,
    const float* __restrict__ al, const float* __restrict__ ar,
    float* __restrict__ out)
{
  const int tid  = threadIdx.x;
  const int lane = tid & 63;
  const int wv   = tid >> 6;      // wave 0..3, owns cols [wv*128, wv*128+128)
  const int c16  = lane & 15;
  const int quad = lane >> 4;
  const int wg   = blockIdx.x;    // 0..4095
  const int R0   = wg * 48;       // global row base (row = b*12 + n)

  __shared__ __align__(16) unsigned short a_lds[2][1536];   // 6 KB  A double-buffer (A-frag layout)
  __shared__ __align__(16) unsigned short hpack[8192];      // 16 KB h B-frag buffer (1 graph/round)
  __shared__ __align__(16) unsigned short alpha_lds[1024];  // 2 KB  alpha [4][16][16] bf16
  __shared__ float elw[4][48];
  __shared__ float erw[4][48];

  f32x4 acc[3][8];
  const f32x4 zero4 = {0.f, 0.f, 0.f, 0.f};
  const s16x8 zero8 = {0,0,0,0,0,0,0,0};
#pragma unroll
  for (int i = 0; i < 3; i++)
#pragma unroll
    for (int j = 0; j < 8; j++) acc[i][j] = zero4;

  // ---- Phase A: h = x @ W (bf16 MFMA, fp32 acc) ----
  const int srow = tid >> 2;          // staging row 0..47 (tid<192)
  const int sq   = tid & 3;           // k-subchunk of 8
  const bool stager = (tid < 192);
  const float* xsrc = x + (R0 + srow) * 512 + sq * 8;
  const int adst = (srow >> 4) * 64 + sq * 16 + (srow & 15);  // uint4 index in a_lds buf

  const s16x8* wps = (const s16x8*)wp;
  s16x8 breg[2][8];

  // prologue: B frags for kt=0 + stage A for kt=0
#pragma unroll
  for (int nt = 0; nt < 8; nt++) breg[0][nt] = wps[(wv*8 + nt)*64 + lane];
  if (stager){
    uint4 v;
    v.x = fpack2(xsrc[0], xsrc[1]); v.y = fpack2(xsrc[2], xsrc[3]);
    v.z = fpack2(xsrc[4], xsrc[5]); v.w = fpack2(xsrc[6], xsrc[7]);
    ((uint4*)a_lds[0])[adst] = v;
  }
  __syncthreads();

#pragma unroll
  for (int kt = 0; kt < 16; ++kt){
    const int buf = kt & 1;
    if (kt < 15){
#pragma unroll
      for (int nt = 0; nt < 8; nt++)
        breg[buf^1][nt] = wps[((kt+1)*32 + wv*8 + nt)*64 + lane];
    }
    float xr[8];
    if (kt < 15 && stager){
      const float* p = xsrc + (kt+1)*32;
#pragma unroll
      for (int i = 0; i < 8; i++) xr[i] = p[i];
    }
    s16x8 af[3];
#pragma unroll
    for (int mt = 0; mt < 3; mt++) af[mt] = ((const s16x8*)a_lds[buf])[mt*64 + lane];
#pragma unroll
    for (int mt = 0; mt < 3; mt++)
#pragma unroll
      for (int nt = 0; nt < 8; nt++)
        acc[mt][nt] = __builtin_amdgcn_mfma_f32_16x16x32_bf16(af[mt], breg[buf][nt], acc[mt][nt], 0, 0, 0);
    if (kt < 15 && stager){
      uint4 v;
      v.x = fpack2(xr[0], xr[1]); v.y = fpack2(xr[2], xr[3]);
      v.z = fpack2(xr[4], xr[5]); v.w = fpack2(xr[6], xr[7]);
      ((uint4*)a_lds[buf^1])[adst] = v;
    }
    __syncthreads();
  }

  // ---- Phase B1: el/er from registers (fp32) ----
  float alv[8], arv[8];
#pragma unroll
  for (int nt = 0; nt < 8; nt++){
    int col = wv*128 + nt*16 + c16;
    alv[nt] = al[col]; arv[nt] = ar[col];
  }
#pragma unroll
  for (int mt = 0; mt < 3; mt++){
#pragma unroll
    for (int r = 0; r < 4; r++){
      float sl = 0.f, sr = 0.f;
#pragma unroll
      for (int nt = 0; nt < 8; nt++){
        float v = acc[mt][nt][r];
        sl += v * alv[nt]; sr += v * arv[nt];
      }
#pragma unroll
      for (int off = 1; off < 16; off <<= 1){
        sl += __shfl_xor(sl, off, 64);
        sr += __shfl_xor(sr, off, 64);
      }
      if (c16 == 0){
        int g = mt*16 + quad*4 + r;
        elw[wv][g] = sl; erw[wv][g] = sr;
      }
    }
  }
  // zero alpha buffer (2 KB) and hpack pad region (rows kb=12..15 of quad'1)
  {
    uint4 z4; z4.x = z4.y = z4.z = z4.w = 0u;
    if (tid < 128) ((uint4*)alpha_lds)[tid] = z4;
#pragma unroll
    for (int i = 0; i < 2; i++){
      int p = tid + 256*i;              // 0..511
      int ntg = p >> 4, s = 16 + (p & 15);
      uint2 z2; z2.x = 0u; z2.y = 0u;
      *(uint2*)&hpack[(ntg*32 + s)*8 + 4] = z2;
    }
  }
  __syncthreads();

  // ---- Phase B2: masked softmax, wave wv handles graph wv, lanes 0..11 ----
  if (lane < 12){
    const int n = lane;
    float el_ = elw[0][wv*12+n] + elw[1][wv*12+n] + elw[2][wv*12+n] + elw[3][wv*12+n];
    float er_ = erw[0][wv*12+n] + erw[1][wv*12+n] + erw[2][wv*12+n] + erw[3][wv*12+n];
    // ADJ_BASE rows packed as 12-bit masks, 4 rows per u64
    const unsigned long long W0 = 0x0FF70FE80FE80FE8ull;
    const unsigned long long W1 = 0x0E3F0E3F01DF0FE8ull;
    const unsigned long long W2 = 0x01DF01DF01DF0E3Full;
    unsigned long long wrow = (n < 4) ? W0 : ((n < 8) ? W1 : W2);
    unsigned rowm = (unsigned)((wrow >> ((n & 3) * 16)) & 0xFFFu);
    const float* am = adjm + (long)(wg*4 + wv) * 144 + n * 12;
    float e[12]; float mx = -3.0e38f;
#pragma unroll
    for (int m = 0; m < 12; m++){
      float erm = __shfl(er_, m, 64);
      float z = el_ + erm;
      z = (z > 0.f) ? z : 0.2f * z;
      bool ok = (m == n) || ((((rowm >> m) & 1u) != 0u) && (am[m] > 0.1f));
      e[m] = ok ? z : -3.0e38f;
      mx = fmaxf(mx, e[m]);
    }
    float s = 0.f; float pr[12];
#pragma unroll
    for (int m = 0; m < 12; m++){
      float p = (e[m] > -1.0e38f) ? __expf(e[m] - mx) : 0.f;
      pr[m] = p; s += p;
    }
    float inv = 1.0f / s;
#pragma unroll
    for (int m = 0; m < 12; m++)
      alpha_lds[(wv*16 + n)*16 + m] = f2bf(pr[m] * inv);
  }
  __syncthreads();

  // ---- Phase B3: out = alpha @ h + x, one graph per round ----
#pragma unroll
  for (int t = 0; t < 4; t++){
    // pack this graph's h rows (from acc regs) into B-frag layout
#pragma unroll
    for (int mt = 0; mt < 3; mt++){
      int r0 = mt*16 + quad*4;
      int bi = r0 / 12;
      if (bi == t){
        int kb0 = r0 - bi*12;           // 0,4,8
        int qp  = kb0 >> 3;             // 0,0,1
        int j0  = kb0 & 7;              // 0,4,0
#pragma unroll
        for (int nt = 0; nt < 8; nt++){
          int ntg = wv*8 + nt;
          uint2 v;
          v.x = fpack2(acc[mt][nt][0], acc[mt][nt][1]);
          v.y = fpack2(acc[mt][nt][2], acc[mt][nt][3]);
          *(uint2*)&hpack[(ntg*32 + qp*16 + c16)*8 + j0] = v;
        }
      }
    }
    __syncthreads();
    {
      s16x8 aA = zero8;
      if (quad < 2) aA = *(const s16x8*)&alpha_lds[(t*16 + c16)*16 + quad*8];
#pragma unroll
      for (int nt = 0; nt < 8; nt++){
        int ntg = wv*8 + nt;
        s16x8 bB = zero8;
        if (quad < 2) bB = *(const s16x8*)&hpack[(ntg*32 + lane)*8];
        f32x4 r4 = __builtin_amdgcn_mfma_f32_16x16x32_bf16(aA, bB, zero4, 0, 0, 0);
        if (quad < 3){
          int base = (R0 + t*12 + quad*4)*512 + ntg*16 + c16;
#pragma unroll
          for (int r = 0; r < 4; r++){
            int a2 = base + r*512;
            out[a2] = r4[r] + x[a2];
          }
        }
      }
    }
    if (t < 3) __syncthreads();
  }
}

extern "C" void kernel_launch(void* const* d_in, const int* in_sizes, int n_in,
                              void* d_out, int out_size, void* d_ws, size_t ws_size,
                              hipStream_t stream) {
  const float* x    = (const float*)d_in[0];
  const float* adjm = (const float*)d_in[1];
  const float* W    = (const float*)d_in[2];
  const float* al   = (const float*)d_in[3];
  const float* ar   = (const float*)d_in[4];
  float* out = (float*)d_out;
  unsigned short* wp = (unsigned short*)d_ws;   // 512 KB packed bf16 W

  k_pack_w<<<1024, 256, 0, stream>>>(W, wp);
  k_gat<<<4096, 256, 0, stream>>>(x, adjm, wp, al, ar, out);
}

// Round 2
// 807.043 us; speedup vs baseline: 1.0775x; 1.0775x over previous
//
#include <hip/hip_runtime.h>
#include <stdint.h>

typedef float f32x4 __attribute__((ext_vector_type(4)));
typedef short s16x8 __attribute__((ext_vector_type(8)));

// fp32 -> bf16 RTNE, packed pair into one u32
__device__ __forceinline__ unsigned int fpack2(float a, float b){
  unsigned int ua = __float_as_uint(a); ua += 0x7FFFu + ((ua >> 16) & 1u);
  unsigned int ub = __float_as_uint(b); ub += 0x7FFFu + ((ub >> 16) & 1u);
  return (ua >> 16) | (ub & 0xFFFF0000u);
}
__device__ __forceinline__ unsigned short f2bf(float f){
  unsigned int u = __float_as_uint(f);
  u += 0x7FFFu + ((u >> 16) & 1u);
  return (unsigned short)(u >> 16);
}

// Pack W fp32 [512][512] row-major -> bf16 in MFMA B-fragment order:
// wp[((kt*32 + ntg)*64 + q*16 + c)*8 + j] = W[kt*32 + q*8 + j][ntg*16 + c]
__global__ __launch_bounds__(256) void k_pack_w(const float* __restrict__ W,
                                                unsigned short* __restrict__ wp){
  int idx = blockIdx.x * 256 + threadIdx.x;   // 0..262143
  int k = idx >> 9, n = idx & 511;
  int kt = k >> 5, kr = k & 31;
  int q  = kr >> 3, j = kr & 7;
  int ntg = n >> 4, c = n & 15;
  wp[((kt*32 + ntg)*64 + q*16 + c)*8 + j] = f2bf(W[idx]);
}

// Fused GAT: 4 graphs (48 rows) per 256-thread workgroup.
// One-shot LDS staging of x (48 KB, XOR-swizzled A-frag layout), barrier-free
// K-loop, epilogue buffers aliased into the staging region.
__global__ __launch_bounds__(256, 3) void k_gat(
    const float* __restrict__ x, const float* __restrict__ adjm,
    const unsigned short* __restrict__ wp,
    const float* __restrict__ al, const float* __restrict__ ar,
    float* __restrict__ out)
{
  const int tid  = threadIdx.x;
  const int lane = tid & 63;
  const int wv   = tid >> 6;      // wave 0..3, owns cols [wv*128, wv*128+128)
  const int c16  = lane & 15;
  const int quad = lane >> 4;
  const int wg   = blockIdx.x;    // 0..4095
  const int R0   = wg * 48;       // global row base (row = b*12 + n)

  __shared__ __align__(16) unsigned char smem[49152];      // 48 KB
  uint4* stage = (uint4*)smem;                             // [3072] phase A
  unsigned short* hpack = (unsigned short*)smem;           // [8192] phase B (aliased)
  unsigned short* alpha = (unsigned short*)(smem + 16384); // [1024]
  float* elw = (float*)(smem + 18432);                     // [4][48]
  float* erw = (float*)(smem + 19200);                     // [4][48]

  // ---- Phase A0: stage all of x-tile (48 rows x 512) as bf16 into LDS ----
  // chunk c = tid + 256*i : row = c>>6, kchunk = c&63 (8 floats each)
  // LDS uint4 index: IDX(kt,mt,q,cc) = (kt*3+mt)*64 + q*16 + (cc ^ q ^ ((kt&3)<<2))
  f32x4 xr[24];
  {
    const float* xb = x + (long)R0 * 512;
#pragma unroll
    for (int i = 0; i < 12; i++){
      int c = tid + 256*i;
      int row = c >> 6, kc = c & 63;
      const float* p = xb + row*512 + kc*8;
      xr[2*i]   = *(const f32x4*)p;
      xr[2*i+1] = *(const f32x4*)(p + 4);
    }
#pragma unroll
    for (int i = 0; i < 12; i++){
      int c = tid + 256*i;
      int row = c >> 6, kc = c & 63;
      int kt = kc >> 2, q = kc & 3;
      int mt = row >> 4, cc = row & 15;
      int idx = ((kt*3 + mt) << 6) + (q << 4) + (cc ^ q ^ ((kt & 3) << 2));
      uint4 v;
      v.x = fpack2(xr[2*i][0], xr[2*i][1]);
      v.y = fpack2(xr[2*i][2], xr[2*i][3]);
      v.z = fpack2(xr[2*i+1][0], xr[2*i+1][1]);
      v.w = fpack2(xr[2*i+1][2], xr[2*i+1][3]);
      stage[idx] = v;
    }
  }
  __syncthreads();

  // ---- Phase A1: h = x @ W, barrier-free K-loop ----
  f32x4 acc[3][8];
  const f32x4 zero4 = {0.f, 0.f, 0.f, 0.f};
  const s16x8 zero8 = {0,0,0,0,0,0,0,0};
#pragma unroll
  for (int i = 0; i < 3; i++)
#pragma unroll
    for (int j = 0; j < 8; j++) acc[i][j] = zero4;

  const s16x8* wps = (const s16x8*)wp;
  const s16x8* sp  = (const s16x8*)smem;
#pragma unroll
  for (int kt = 0; kt < 16; ++kt){
    s16x8 breg[8];
#pragma unroll
    for (int nt = 0; nt < 8; nt++)
      breg[nt] = wps[(kt*32 + wv*8 + nt)*64 + lane];
    const int cxs = c16 ^ quad ^ ((kt & 3) << 2);
#pragma unroll
    for (int mt = 0; mt < 3; mt++){
      s16x8 af = sp[((kt*3 + mt) << 6) + (quad << 4) + cxs];
#pragma unroll
      for (int nt = 0; nt < 8; nt++)
        acc[mt][nt] = __builtin_amdgcn_mfma_f32_16x16x32_bf16(af, breg[nt], acc[mt][nt], 0, 0, 0);
    }
  }
  __syncthreads();   // staging region dead; epilogue buffers may now alias it

  // ---- Phase B1: el/er from registers (fp32) ----
  float alv[8], arv[8];
#pragma unroll
  for (int nt = 0; nt < 8; nt++){
    int col = wv*128 + nt*16 + c16;
    alv[nt] = al[col]; arv[nt] = ar[col];
  }
#pragma unroll
  for (int mt = 0; mt < 3; mt++){
#pragma unroll
    for (int r = 0; r < 4; r++){
      float sl = 0.f, sr = 0.f;
#pragma unroll
      for (int nt = 0; nt < 8; nt++){
        float v = acc[mt][nt][r];
        sl += v * alv[nt]; sr += v * arv[nt];
      }
#pragma unroll
      for (int off = 1; off < 16; off <<= 1){
        sl += __shfl_xor(sl, off, 64);
        sr += __shfl_xor(sr, off, 64);
      }
      if (c16 == 0){
        int g = mt*16 + quad*4 + r;
        elw[wv*48 + g] = sl; erw[wv*48 + g] = sr;
      }
    }
  }
  // zero alpha buffer (2 KB) and hpack pad region (k rows 12..15)
  {
    uint4 z4; z4.x = z4.y = z4.z = z4.w = 0u;
    if (tid < 128) ((uint4*)alpha)[tid] = z4;
#pragma unroll
    for (int i = 0; i < 2; i++){
      int p = tid + 256*i;              // 0..511
      int ntg = p >> 4, s = 16 + (p & 15);
      uint2 z2; z2.x = 0u; z2.y = 0u;
      *(uint2*)&hpack[(ntg*32 + s)*8 + 4] = z2;
    }
  }
  __syncthreads();

  // ---- Phase B2: masked softmax, wave wv handles graph wv, lanes 0..11 ----
  if (lane < 12){
    const int n = lane;
    float el_ = elw[0*48 + wv*12+n] + elw[1*48 + wv*12+n] + elw[2*48 + wv*12+n] + elw[3*48 + wv*12+n];
    float er_ = erw[0*48 + wv*12+n] + erw[1*48 + wv*12+n] + erw[2*48 + wv*12+n] + erw[3*48 + wv*12+n];
    // ADJ_BASE rows packed as 12-bit masks, 4 rows per u64
    const unsigned long long W0 = 0x0FF70FE80FE80FE8ull;
    const unsigned long long W1 = 0x0E3F0E3F01DF0FE8ull;
    const unsigned long long W2 = 0x01DF01DF01DF0E3Full;
    unsigned long long wrow = (n < 4) ? W0 : ((n < 8) ? W1 : W2);
    unsigned rowm = (unsigned)((wrow >> ((n & 3) * 16)) & 0xFFFu);
    const float* am = adjm + (long)(wg*4 + wv) * 144 + n * 12;
    float e[12]; float mx = -3.0e38f;
#pragma unroll
    for (int m = 0; m < 12; m++){
      float erm = __shfl(er_, m, 64);
      float z = el_ + erm;
      z = (z > 0.f) ? z : 0.2f * z;
      bool ok = (m == n) || ((((rowm >> m) & 1u) != 0u) && (am[m] > 0.1f));
      e[m] = ok ? z : -3.0e38f;
      mx = fmaxf(mx, e[m]);
    }
    float s = 0.f; float pr[12];
#pragma unroll
    for (int m = 0; m < 12; m++){
      float p = (e[m] > -1.0e38f) ? __expf(e[m] - mx) : 0.f;
      pr[m] = p; s += p;
    }
    float inv = 1.0f / s;
#pragma unroll
    for (int m = 0; m < 12; m++)
      alpha[(wv*16 + n)*16 + m] = f2bf(pr[m] * inv);
  }
  __syncthreads();

  // ---- Phase B3: out = alpha @ h + x, one graph per round ----
#pragma unroll
  for (int t = 0; t < 4; t++){
    // pack this graph's h rows (from acc regs) into B-frag layout
#pragma unroll
    for (int mt = 0; mt < 3; mt++){
      int r0 = mt*16 + quad*4;
      int bi = r0 / 12;
      if (bi == t){
        int kb0 = r0 - bi*12;           // 0,4,8
        int qp  = kb0 >> 3;             // 0,0,1
        int j0  = kb0 & 7;              // 0,4,0
#pragma unroll
        for (int nt = 0; nt < 8; nt++){
          int ntg = wv*8 + nt;
          uint2 v;
          v.x = fpack2(acc[mt][nt][0], acc[mt][nt][1]);
          v.y = fpack2(acc[mt][nt][2], acc[mt][nt][3]);
          *(uint2*)&hpack[(ntg*32 + qp*16 + c16)*8 + j0] = v;
        }
      }
    }
    __syncthreads();
    {
      s16x8 aA = zero8;
      if (quad < 2) aA = *(const s16x8*)&alpha[(t*16 + c16)*16 + quad*8];
#pragma unroll
      for (int nt = 0; nt < 8; nt++){
        int ntg = wv*8 + nt;
        s16x8 bB = zero8;
        if (quad < 2) bB = *(const s16x8*)&hpack[(ntg*32 + lane)*8];
        f32x4 r4 = __builtin_amdgcn_mfma_f32_16x16x32_bf16(aA, bB, zero4, 0, 0, 0);
        if (quad < 3){
          int base = (R0 + t*12 + quad*4)*512 + ntg*16 + c16;
#pragma unroll
          for (int r = 0; r < 4; r++){
            int a2 = base + r*512;
            out[a2] = r4[r] + x[a2];
          }
        }
      }
    }
    if (t < 3) __syncthreads();
  }
}

extern "C" void kernel_launch(void* const* d_in, const int* in_sizes, int n_in,
                              void* d_out, int out_size, void* d_ws, size_t ws_size,
                              hipStream_t stream) {
  const float* x    = (const float*)d_in[0];
  const float* adjm = (const float*)d_in[1];
  const float* W    = (const float*)d_in[2];
  const float* al   = (const float*)d_in[3];
  const float* ar   = (const float*)d_in[4];
  float* out = (float*)d_out;
  unsigned short* wp = (unsigned short*)d_ws;   // 512 KB packed bf16 W

  k_pack_w<<<1024, 256, 0, stream>>>(W, wp);
  k_gat<<<4096, 256, 0, stream>>>(x, adjm, wp, al, ar, out);
}